// Round 2
// baseline (840.590 us; speedup 1.0000x reference)
//
#include <hip/hip_runtime.h>

typedef __bf16 bf16;
typedef __bf16 bf16x8 __attribute__((ext_vector_type(8)));
typedef float  f32x4  __attribute__((ext_vector_type(4)));

#define MFMA16(a, b, c) __builtin_amdgcn_mfma_f32_16x16x32_bf16((a), (b), (c), 0, 0, 0)

constexpr int N_NODES = 50000;
constexpr int N_EDGES = 800000;
constexpr int D = 64;

constexpr int XS_STRIDE = 200;  // 192 + 8 pad
constexpr int HS_STRIDE = 72;   // 64 + 8 pad
constexpr int X2_STRIDE = 136;  // 128 + 8 pad

constexpr size_t SBUF_ELEMS = (size_t)N_NODES * D;            // 3.2M f32
constexpr size_t SBUF_BYTES = SBUF_ELEMS * sizeof(float);     // 12.8 MB

// ---------------------------------------------------------------------------
// Dtype detection. flags[0]=1 -> float arrays are f32 (else bf16).
//                  flags[1]=1 -> edge_index is int64 (else int32).
// bf16 data: even halfwords are genuine Gaussian bf16 (exp in [97,157] ~100%).
// f32 data:  even halfwords are random mantissa bits (~24% in that band).
// int64 idx: odd int32 words are all 0 (values < 50000 -> high word 0).
// ---------------------------------------------------------------------------
__global__ void detect_kernel(const void* __restrict__ feat,
                              const void* __restrict__ eidx,
                              int* __restrict__ flags)
{
    __shared__ int c_bf[64], c_nz[64];
    const int t = threadIdx.x;  // 64 threads
    const unsigned short* h = (const unsigned short*)feat;
    int c = 0;
    #pragma unroll
    for (int j = 0; j < 8; ++j) {
        const unsigned short v = h[(t * 8 + j) * 2];   // even halfword positions
        const int e8 = (v >> 7) & 0xFF;
        c += (e8 >= 97 && e8 <= 157) ? 1 : 0;
    }
    c_bf[t] = c;
    const int* ei = (const int*)eidx;
    int nz = 0;
    #pragma unroll
    for (int j = 0; j < 2; ++j)
        nz += (ei[(t * 2 + j) * 2 + 1] != 0) ? 1 : 0;  // odd int32 positions
    c_nz[t] = nz;
    __syncthreads();
    if (t == 0) {
        int s = 0, s2 = 0;
        for (int i = 0; i < 64; ++i) { s += c_bf[i]; s2 += c_nz[i]; }
        flags[0] = (s < 384) ? 1 : 0;   // <75% bf16-plausible -> f32
        flags[1] = (s2 < 4) ? 1 : 0;    // odd words ~all zero -> int64
    }
}

// ---------------------------------------------------------------------------
// Dual-dtype load helpers (element offsets are dtype-invariant).
// ---------------------------------------------------------------------------
__device__ inline bf16x8 ld8(const void* base, size_t off, int f32f) {
    if (f32f) {
        const float* p = (const float*)base + off;
        const float4 a = *(const float4*)p;
        const float4 b = *(const float4*)(p + 4);
        bf16x8 r;
        r[0] = (bf16)a.x; r[1] = (bf16)a.y; r[2] = (bf16)a.z; r[3] = (bf16)a.w;
        r[4] = (bf16)b.x; r[5] = (bf16)b.y; r[6] = (bf16)b.z; r[7] = (bf16)b.w;
        return r;
    }
    return *(const bf16x8*)((const bf16*)base + off);
}

__device__ inline float ldf(const void* base, int i, int f32f) {
    return f32f ? ((const float*)base)[i] : (float)((const bf16*)base)[i];
}

__device__ inline int gidx(const void* e, size_t i, int i64f) {
    return i64f ? (int)((const long long*)e)[i] : ((const int*)e)[i];
}

// ---------------------------------------------------------------------------
// Kernel A: per-edge MLP + scatter-add. One block = 64 edges, 4 waves.
// ---------------------------------------------------------------------------
__global__ __launch_bounds__(256) void edge_kernel(
    const void* __restrict__ feat, const void* __restrict__ eidx,
    const void* __restrict__ efeat,
    const void* __restrict__ W1, const void* __restrict__ b1,
    const void* __restrict__ W2, const void* __restrict__ b2,
    float* __restrict__ sbuf, const int* __restrict__ flags)
{
    __shared__ bf16 xs[64 * XS_STRIDE];
    __shared__ bf16 h1s[64 * HS_STRIDE];
    __shared__ int  srcs[64];
    __shared__ int  fl[2];

    const int t  = threadIdx.x;
    const int e0 = blockIdx.x * 64;

    if (t < 2) fl[t] = flags[t];
    __syncthreads();
    const int F32 = fl[0], I64 = fl[1];

    if (t < 64) srcs[t] = gidx(eidx, e0 + t, I64);

    // Stage X tile [64 x 192]: 3 parts x 8 chunks of 8 elements per row.
    for (int i = t; i < 64 * 24; i += 256) {
        const int e    = i / 24;
        const int c    = i - e * 24;
        const int part = c >> 3;
        const int cc   = c & 7;
        size_t off;
        const void* base;
        if (part == 0)      { base = feat;  off = (size_t)gidx(eidx, e0 + e, I64) * D + cc * 8; }
        else if (part == 1) { base = efeat; off = (size_t)(e0 + e) * D + cc * 8; }
        else                { base = feat;  off = (size_t)gidx(eidx, (size_t)N_EDGES + e0 + e, I64) * D + cc * 8; }
        *(bf16x8*)&xs[e * XS_STRIDE + part * 64 + cc * 8] = ld8(base, off, F32);
    }
    __syncthreads();

    const int wave = t >> 6;
    const int lane = t & 63;
    const int m0   = wave * 16;
    const int lrow = lane & 15;
    const int quad = lane >> 4;

    // GEMM1: K=192 (6 k-steps), N=64 (4 tiles of 16).
    f32x4 acc[4] = {{0,0,0,0},{0,0,0,0},{0,0,0,0},{0,0,0,0}};
    #pragma unroll
    for (int k = 0; k < 6; ++k) {
        const bf16x8 a = *(const bf16x8*)&xs[(m0 + lrow) * XS_STRIDE + k * 32 + quad * 8];
        #pragma unroll
        for (int n = 0; n < 4; ++n) {
            const bf16x8 b = ld8(W1, (size_t)(n * 16 + lrow) * 192 + k * 32 + quad * 8, F32);
            acc[n] = MFMA16(a, b, acc[n]);
        }
    }

    // ReLU + b1; C-layout (row=quad*4+r, col=n*16+lrow) -> row-major LDS.
    #pragma unroll
    for (int n = 0; n < 4; ++n) {
        const int col  = n * 16 + lrow;
        const float bb = ldf(b1, col, F32);
        #pragma unroll
        for (int r = 0; r < 4; ++r) {
            float v = acc[n][r] + bb;
            v = v > 0.f ? v : 0.f;
            h1s[(m0 + quad * 4 + r) * HS_STRIDE + col] = (bf16)v;
        }
    }
    __syncthreads();

    // GEMM2: K=64 (2 k-steps).
    f32x4 acc2[4] = {{0,0,0,0},{0,0,0,0},{0,0,0,0},{0,0,0,0}};
    #pragma unroll
    for (int k = 0; k < 2; ++k) {
        const bf16x8 a = *(const bf16x8*)&h1s[(m0 + lrow) * HS_STRIDE + k * 32 + quad * 8];
        #pragma unroll
        for (int n = 0; n < 4; ++n) {
            const bf16x8 b = ld8(W2, (size_t)(n * 16 + lrow) * D + k * 32 + quad * 8, F32);
            acc2[n] = MFMA16(a, b, acc2[n]);
        }
    }

    // Scatter h2 into sbuf[src] (f32 atomics).
    #pragma unroll
    for (int n = 0; n < 4; ++n) {
        const int col  = n * 16 + lrow;
        const float bb = ldf(b2, col, F32);
        #pragma unroll
        for (int r = 0; r < 4; ++r) {
            const int e = m0 + quad * 4 + r;
            atomicAdd(&sbuf[(size_t)srcs[e] * D + col], acc2[n][r] + bb);
        }
    }
}

// ---------------------------------------------------------------------------
// Kernel B: per-node MLP. One block = 64 nodes.
// ---------------------------------------------------------------------------
__global__ __launch_bounds__(256) void node_kernel(
    const void* __restrict__ feat, const float* __restrict__ sbuf,
    const void* __restrict__ W3, const void* __restrict__ b3,
    const void* __restrict__ W4, const void* __restrict__ b4,
    void* __restrict__ out, const int* __restrict__ flags)
{
    __shared__ bf16 xs[64 * X2_STRIDE];
    __shared__ bf16 h3s[64 * HS_STRIDE];
    __shared__ int  fl[1];

    const int t  = threadIdx.x;
    const int r0 = blockIdx.x * 64;

    if (t == 0) fl[0] = flags[0];
    __syncthreads();
    const int F32 = fl[0];

    for (int i = t; i < 64 * 8; i += 256) {
        const int r    = i >> 3;
        const int c    = i & 7;
        const int node = r0 + r;
        bf16x8 fv = {0,0,0,0,0,0,0,0};
        bf16x8 sv = {0,0,0,0,0,0,0,0};
        if (node < N_NODES) {
            fv = ld8(feat, (size_t)node * D + c * 8, F32);
            const float4 sa = *(const float4*)&sbuf[(size_t)node * D + c * 8];
            const float4 sb = *(const float4*)&sbuf[(size_t)node * D + c * 8 + 4];
            sv[0] = (bf16)((float)fv[0] + sa.x);
            sv[1] = (bf16)((float)fv[1] + sa.y);
            sv[2] = (bf16)((float)fv[2] + sa.z);
            sv[3] = (bf16)((float)fv[3] + sa.w);
            sv[4] = (bf16)((float)fv[4] + sb.x);
            sv[5] = (bf16)((float)fv[5] + sb.y);
            sv[6] = (bf16)((float)fv[6] + sb.z);
            sv[7] = (bf16)((float)fv[7] + sb.w);
        }
        *(bf16x8*)&xs[r * X2_STRIDE + c * 8]      = fv;
        *(bf16x8*)&xs[r * X2_STRIDE + 64 + c * 8] = sv;
    }
    __syncthreads();

    const int wave = t >> 6;
    const int lane = t & 63;
    const int m0   = wave * 16;
    const int lrow = lane & 15;
    const int quad = lane >> 4;

    // GEMM3: K=128 (4 k-steps)
    f32x4 acc[4] = {{0,0,0,0},{0,0,0,0},{0,0,0,0},{0,0,0,0}};
    #pragma unroll
    for (int k = 0; k < 4; ++k) {
        const bf16x8 a = *(const bf16x8*)&xs[(m0 + lrow) * X2_STRIDE + k * 32 + quad * 8];
        #pragma unroll
        for (int n = 0; n < 4; ++n) {
            const bf16x8 b = ld8(W3, (size_t)(n * 16 + lrow) * 128 + k * 32 + quad * 8, F32);
            acc[n] = MFMA16(a, b, acc[n]);
        }
    }

    #pragma unroll
    for (int n = 0; n < 4; ++n) {
        const int col  = n * 16 + lrow;
        const float bb = ldf(b3, col, F32);
        #pragma unroll
        for (int r = 0; r < 4; ++r) {
            float v = acc[n][r] + bb;
            v = v > 0.f ? v : 0.f;
            h3s[(m0 + quad * 4 + r) * HS_STRIDE + col] = (bf16)v;
        }
    }
    __syncthreads();

    // GEMM4: K=64 (2 k-steps)
    f32x4 acc2[4] = {{0,0,0,0},{0,0,0,0},{0,0,0,0},{0,0,0,0}};
    #pragma unroll
    for (int k = 0; k < 2; ++k) {
        const bf16x8 a = *(const bf16x8*)&h3s[(m0 + lrow) * HS_STRIDE + k * 32 + quad * 8];
        #pragma unroll
        for (int n = 0; n < 4; ++n) {
            const bf16x8 b = ld8(W4, (size_t)(n * 16 + lrow) * D + k * 32 + quad * 8, F32);
            acc2[n] = MFMA16(a, b, acc2[n]);
        }
    }

    #pragma unroll
    for (int n = 0; n < 4; ++n) {
        const int col  = n * 16 + lrow;
        const float bb = ldf(b4, col, F32);
        #pragma unroll
        for (int r = 0; r < 4; ++r) {
            const int node = r0 + m0 + quad * 4 + r;
            if (node < N_NODES) {
                const float v = acc2[n][r] + bb;
                if (F32) ((float*)out)[(size_t)node * D + col] = v;
                else     ((bf16*)out)[(size_t)node * D + col] = (bf16)v;
            }
        }
    }
}

extern "C" void kernel_launch(void* const* d_in, const int* in_sizes, int n_in,
                              void* d_out, int out_size, void* d_ws, size_t ws_size,
                              hipStream_t stream) {
    const void* feat  = d_in[0];
    const void* eidx  = d_in[1];
    const void* efeat = d_in[2];
    const void* W1    = d_in[3];
    const void* b1    = d_in[4];
    const void* W2    = d_in[5];
    const void* b2    = d_in[6];
    const void* W3    = d_in[7];
    const void* b3    = d_in[8];
    const void* W4    = d_in[9];
    const void* b4    = d_in[10];

    float* sbuf = (float*)d_ws;                          // 12.8 MB f32 accumulator
    int*   flags = (int*)((char*)d_ws + SBUF_BYTES);     // detection flags after it

    detect_kernel<<<1, 64, 0, stream>>>(feat, eidx, flags);
    hipMemsetAsync(sbuf, 0, SBUF_BYTES, stream);
    edge_kernel<<<N_EDGES / 64, 256, 0, stream>>>(feat, eidx, efeat, W1, b1, W2, b2, sbuf, flags);
    node_kernel<<<(N_NODES + 63) / 64, 256, 0, stream>>>(feat, sbuf, W3, b3, W4, b4, d_out, flags);
}